// Round 11
// baseline (2663.143 us; speedup 1.0000x reference)
//
#include <hip/hip_runtime.h>

#define BATCH 512
#define NN    32
#define NVT   32
#define HS    501
#define VS    533
#define KP    512

typedef short bf16x8 __attribute__((ext_vector_type(8)));
typedef float f32x4  __attribute__((ext_vector_type(4)));

__device__ __forceinline__ unsigned short f2bf(float f) {
    unsigned int u = __float_as_uint(f);
    u += 0x7fffu + ((u >> 16) & 1u);
    return (unsigned short)(u >> 16);
}
__device__ __forceinline__ float bf2f(unsigned short s) {
    return __uint_as_float(((unsigned int)s) << 16);
}
__device__ __forceinline__ float sigmoidf_(float x) { return 1.0f / (1.0f + __expf(-x)); }
__device__ __forceinline__ float tanhf_(float x)    { return 1.0f - 2.0f / (1.0f + __expf(2.0f * x)); }

// swizzled ushort index for [R][512] bf16 LDS tile (row stride 1024 B)
__device__ __forceinline__ int idx512(int row, int k) {
    return (((row << 10) + (k << 1)) ^ ((row & 7) << 4)) >> 1;
}

#define N_WHH  (3 * KP * KP)
#define N_WGM  (2 * KP * KP)
#define N_GI   (3 * NVT * KP)
#define N_IDW  (2 * NN * KP)
#define N_WRT  (KP * NN)
#define N_ADJC (BATCH * NN)
#define N_TOT  (N_WHH + N_WGM + N_GI + N_IDW + N_WRT + N_ADJC)

// One-time: bf16 weight repack (b_hh folded at k=501), gi table, id/bg table,
// WregT, adjacency column bitmasks.
__global__ void prep_kernel(const float* __restrict__ W_hh, const float* __restrict__ Wg,
                            const float* __restrict__ Wm, const float* __restrict__ W_ih,
                            const float* __restrict__ b_ih, const float* __restrict__ b_hh,
                            const float* __restrict__ bg, const float* __restrict__ W_reg,
                            const float* __restrict__ adj,
                            unsigned short* __restrict__ Whh_p, unsigned short* __restrict__ Wgm_p,
                            float* __restrict__ gi_tab, float* __restrict__ idw,
                            float* __restrict__ WregT, unsigned int* __restrict__ adjcG)
{
    for (int i = blockIdx.x * blockDim.x + threadIdx.x; i < N_TOT; i += gridDim.x * blockDim.x) {
        int j = i;
        if (j < N_WHH) {
            int g = j >> 18, rem = j & (KP * KP - 1);
            int h = rem >> 9, k = rem & (KP - 1);
            float val = 0.0f;
            if (h < HS) {
                if (k < HS)        val = W_hh[(size_t)(g * HS + h) * HS + k];
                else if (k == HS)  val = b_hh[g * HS + h];   // bias folded at k=501
            }
            Whh_p[j] = f2bf(val);
            continue;
        }
        j -= N_WHH;
        if (j < N_WGM) {
            int m = j >> 18, rem = j & (KP * KP - 1);
            int h = rem >> 9, k = rem & (KP - 1);
            const float* src = m ? Wm : Wg;
            Wgm_p[j] = (h < HS && k < HS) ? f2bf(src[(size_t)h * VS + k]) : (unsigned short)0;
            continue;
        }
        j -= N_WGM;
        if (j < N_GI) {
            int g = j >> 14, typ = (j >> 9) & 31, h = j & (KP - 1);
            gi_tab[j] = (h < HS) ? (W_ih[(size_t)(g * HS + h) * NVT + typ] + b_ih[g * HS + h]) : 0.0f;
            continue;
        }
        j -= N_GI;
        if (j < N_IDW) {
            int m = j >> 14, v = (j >> 9) & 31, h = j & (KP - 1);
            float val = 0.0f;
            if (h < HS)
                val = m ? Wm[(size_t)h * VS + HS + v]
                        : (Wg[(size_t)h * VS + HS + v] + bg[h]);
            idw[j] = val;
            continue;
        }
        j -= N_IDW;
        if (j < N_WRT) {
            int k = j >> 5, ii = j & 31;
            WregT[j] = (k < HS) ? W_reg[(size_t)ii * HS + k] : 0.0f;
            continue;
        }
        j -= N_WRT;
        {
            int b = j >> 5, vp = j & 31;
            unsigned int bits = 0;
            #pragma unroll
            for (int u = 0; u < 32; u++)
                bits |= (adj[((size_t)b * NN + u) * NN + vp] != 0.0f ? 1u : 0u) << u;
            adjcG[j] = bits;
        }
    }
}

// One fused kernel per DAG step v. Grid (8 hy, 16 bx), block 512 (8 waves).
// Block: 32 batch rows (bb..bb+31), gru h-slice hy*64..hy*64+63.
//  phase1 (v>0): G_{v-1} = sigmoid(Hv_{v-1} @ Wg^T + id)·(Hv_{v-1} @ Wm^T + id)
//                full 512 h per block (8x hy-redundant), -> GLds (+Gbuf if hy==0)
//  phase2: Msg_v[32b,512h] = sum_{u} edge(u,v)·G_u  (bitmask gather) -> LDS
//  phase3: gh = Msg_v @ Whh^T (3 gates, own 64 h) + GRU epilogue -> HvB
__global__ __launch_bounds__(512) void step_kernel(
    const unsigned short* __restrict__ Whh,   // [3*512][512] bf16 (k=501 = b_hh)
    const unsigned short* __restrict__ Wgm,   // [2*512][512] bf16
    const float* __restrict__ gi_tab,         // [3][32][512]
    const float* __restrict__ idw,            // [2][32][512]
    const int*   __restrict__ types,          // [512][32]
    const unsigned int* __restrict__ adjcG,   // [512][32] bitmask over u
    unsigned short* __restrict__ Gbuf,        // [32 u][512 b][512 h] bf16
    unsigned short* __restrict__ HvB,         // [512][512] bf16
    float* __restrict__ HvF,                  // [512][512] f32 (last step only)
    int v)
{
    __shared__ unsigned short GLds[32 * KP];   // G_{v-1}, plain layout      (32 KB)
    __shared__ unsigned short Msgb[32 * KP];   // Msg_v bf16, swizzled       (32 KB)
    __shared__ float          MsgFl[32 * KP];  // Msg_v f32 (GRU blend)      (64 KB)

    const int t = threadIdx.x;
    const int hy = blockIdx.x;                 // 0..7 (== XCD for this grid)
    const int bb = blockIdx.y * 32;            // batch base
    const int lane = t & 63, w = t >> 6;       // 8 waves
    const int c16 = lane & 15, kg = lane >> 4;
    const int p = w & 1, q = w >> 1;           // batch half (16 rows), col quarter

    // ---------------- phase 1: G_{v-1} over full 512 h ----------------
    if (v > 0) {
        f32x4 ag[8], am[8];
        #pragma unroll
        for (int i = 0; i < 8; i++) { ag[i] = (f32x4){0.f,0.f,0.f,0.f}; am[i] = ag[i]; }
        const unsigned short* Ar = HvB + (((size_t)(bb + p * 16 + c16)) << 9) + kg * 8;
        const unsigned short* wg[8];
        const unsigned short* wm[8];
        #pragma unroll
        for (int i = 0; i < 8; i++) {
            wg[i] = Wgm + (((size_t)(q * 128 + i * 16 + c16)) << 9) + kg * 8;
            wm[i] = wg[i] + ((size_t)KP << 9);
        }
        #pragma unroll
        for (int kk = 0; kk < 16; kk++) {
            const bf16x8 af = *(const bf16x8*)(Ar + kk * 32);
            #pragma unroll
            for (int i = 0; i < 8; i++) {
                ag[i] = __builtin_amdgcn_mfma_f32_16x16x32_bf16(
                    af, *(const bf16x8*)(wg[i] + kk * 32), ag[i], 0, 0, 0);
                am[i] = __builtin_amdgcn_mfma_f32_16x16x32_bf16(
                    af, *(const bf16x8*)(wm[i] + kk * 32), am[i], 0, 0, 0);
            }
        }
        #pragma unroll
        for (int i = 0; i < 8; i++) {
            const int h = q * 128 + i * 16 + c16;
            const bool ok = (h < HS);
            const float id0 = ok ? idw[(0 * NN + (v - 1)) * KP + h] : 0.0f;
            const float id1 = ok ? idw[(1 * NN + (v - 1)) * KP + h] : 0.0f;
            #pragma unroll
            for (int j = 0; j < 4; j++) {
                const int bl = p * 16 + kg * 4 + j;
                float gq = 0.0f;
                if (ok) gq = sigmoidf_(ag[i][j] + id0) * (am[i][j] + id1);
                const unsigned short gb = f2bf(gq);
                GLds[bl * KP + h] = gb;
                if (hy == 0)
                    Gbuf[(((size_t)(v - 1) << 9) + (bb + bl)) * KP + h] = gb;
            }
        }
    }
    __syncthreads();

    // ---------------- phase 2: Msg_v gather (32 h per thread) ----------------
    {
        const int bl = t >> 4, h0 = (t & 15) * 32;
        float msg[32];
        #pragma unroll
        for (int x = 0; x < 32; x++) msg[x] = 0.0f;
        unsigned int mask = adjcG[(bb + bl) * NN + v];          // bits u < v (triu)
        if (v > 0 && ((mask >> (v - 1)) & 1u)) {                // u == v-1 from LDS
            #pragma unroll
            for (int g8 = 0; g8 < 4; g8++) {
                const bf16x8 a = *(const bf16x8*)&GLds[bl * KP + h0 + g8 * 8];
                #pragma unroll
                for (int x = 0; x < 8; x++) msg[g8 * 8 + x] += bf2f((unsigned short)a[x]);
            }
            mask &= ~(1u << (v - 1));
        }
        while (mask) {                                           // u < v-1 from Gbuf
            const int u = __builtin_ctz(mask); mask &= mask - 1u;
            const unsigned short* gp = Gbuf + (((size_t)u << 9) + (bb + bl)) * KP + h0;
            #pragma unroll
            for (int g8 = 0; g8 < 4; g8++) {
                const bf16x8 a = *(const bf16x8*)(gp + g8 * 8);
                #pragma unroll
                for (int x = 0; x < 8; x++) msg[g8 * 8 + x] += bf2f((unsigned short)a[x]);
            }
        }
        if (h0 <= HS && HS < h0 + 32) msg[HS - h0] = 1.0f;       // bias column k=501
        #pragma unroll
        for (int g8 = 0; g8 < 4; g8++) {
            bf16x8 mb;
            #pragma unroll
            for (int x = 0; x < 8; x++) mb[x] = (short)f2bf(msg[g8 * 8 + x]);
            *(bf16x8*)&Msgb[idx512(bl, h0 + g8 * 8)] = mb;
        }
        #pragma unroll
        for (int x = 0; x < 32; x++) MsgFl[bl * KP + h0 + x] = msg[x];
    }
    __syncthreads();

    // ---------------- phase 3: gru GEMM (own 64 h) + GRU epilogue ----------------
    {
        const int ht = hy * 64 + q * 16;
        f32x4 a0 = {0.f,0.f,0.f,0.f}, a1 = a0, a2 = a0;
        const unsigned short* w0 = Whh + (((size_t)(0 * KP + ht + c16)) << 9) + kg * 8;
        const unsigned short* w1 = Whh + (((size_t)(1 * KP + ht + c16)) << 9) + kg * 8;
        const unsigned short* w2 = Whh + (((size_t)(2 * KP + ht + c16)) << 9) + kg * 8;
        #pragma unroll
        for (int kk = 0; kk < 16; kk++) {
            const bf16x8 af = *(const bf16x8*)&Msgb[idx512(p * 16 + c16, kg * 8 + kk * 32)];
            a0 = __builtin_amdgcn_mfma_f32_16x16x32_bf16(af, *(const bf16x8*)(w0 + kk * 32), a0, 0, 0, 0);
            a1 = __builtin_amdgcn_mfma_f32_16x16x32_bf16(af, *(const bf16x8*)(w1 + kk * 32), a1, 0, 0, 0);
            a2 = __builtin_amdgcn_mfma_f32_16x16x32_bf16(af, *(const bf16x8*)(w2 + kk * 32), a2, 0, 0, 0);
        }
        const int h = ht + c16;
        const bool ok = (h < HS);
        const bool last = (v == NN - 1);
        #pragma unroll
        for (int j = 0; j < 4; j++) {
            const int bl = p * 16 + kg * 4 + j;
            const int b  = bb + bl;
            float hv = 0.0f;
            if (ok) {
                const int typ = types[b * NN + v];
                const float gr = gi_tab[(0 * NVT + typ) * KP + h];
                const float gz = gi_tab[(1 * NVT + typ) * KP + h];
                const float gn = gi_tab[(2 * NVT + typ) * KP + h];
                const float hmsg = MsgFl[bl * KP + h];
                const float r = sigmoidf_(gr + a0[j]);
                const float z = sigmoidf_(gz + a1[j]);
                const float n = tanhf_(gn + r * a2[j]);
                hv = (1.0f - z) * n + z * hmsg;
            }
            HvB[((size_t)b << 9) + h] = f2bf(hv);
            if (last) HvF[((size_t)b << 9) + h] = hv;
        }
    }
}

// mu = Hv31 @ W_reg^T + b_reg
__global__ __launch_bounds__(256) void final_kernel(
    const float* __restrict__ HvF,       // [512][512]
    const float* __restrict__ WregT,     // [512][32]
    const float* __restrict__ b_reg,     // [32]
    float* __restrict__ out)             // [512][32]
{
    const int t = blockIdx.x * 256 + threadIdx.x;
    const int b = t >> 5, i = t & 31;
    float s = b_reg[i];
    const float* hp = HvF + ((size_t)b << 9);
    #pragma unroll 4
    for (int k = 0; k < KP; k++) s += hp[k] * WregT[k * 32 + i];
    out[b * 32 + i] = s;
}

extern "C" void kernel_launch(void* const* d_in, const int* in_sizes, int n_in,
                              void* d_out, int out_size, void* d_ws, size_t ws_size,
                              hipStream_t stream) {
    const int*   node_types = (const int*)  d_in[0];
    const float* adj        = (const float*)d_in[1];
    const float* Wg         = (const float*)d_in[2];
    const float* bg         = (const float*)d_in[3];
    const float* Wm         = (const float*)d_in[4];
    const float* W_ih       = (const float*)d_in[5];
    const float* b_ih       = (const float*)d_in[6];
    const float* W_hh       = (const float*)d_in[7];
    const float* b_hh       = (const float*)d_in[8];
    const float* W_reg      = (const float*)d_in[9];
    const float* b_reg      = (const float*)d_in[10];
    float* out = (float*)d_out;

    char* p = (char*)d_ws;
    unsigned short* Whh_p = (unsigned short*)p; p += (size_t)N_WHH * 2;
    unsigned short* Wgm_p = (unsigned short*)p; p += (size_t)N_WGM * 2;
    float* gi_tab = (float*)p; p += (size_t)N_GI * 4;
    float* idw    = (float*)p; p += (size_t)N_IDW * 4;
    float* WregT  = (float*)p; p += (size_t)N_WRT * 4;
    float* HvF    = (float*)p; p += (size_t)BATCH * KP * 4;
    unsigned short* HvB = (unsigned short*)p; p += (size_t)BATCH * KP * 2;
    unsigned int* adjcG = (unsigned int*)p;  p += (size_t)N_ADJC * 4;
    unsigned short* Gbuf = (unsigned short*)p; p += (size_t)NN * BATCH * KP * 2;

    prep_kernel<<<2048, 256, 0, stream>>>(W_hh, Wg, Wm, W_ih, b_ih, b_hh, bg, W_reg, adj,
                                          Whh_p, Wgm_p, gi_tab, idw, WregT, adjcG);

    dim3 grd(8, 16);   // (hy, bx): 128 blocks; bid%8 == hy -> XCD-aligned h-slices
    for (int v = 0; v < NN; v++)
        step_kernel<<<grd, 512, 0, stream>>>(Whh_p, Wgm_p, gi_tab, idw, node_types,
                                             adjcG, Gbuf, HvB, HvF, v);
    final_kernel<<<(BATCH * NN) / 256, 256, 0, stream>>>(HvF, WregT, b_reg, out);
}

// Round 12
// 447.220 us; speedup vs baseline: 5.9549x; 5.9549x over previous
//
#include <hip/hip_runtime.h>

#define BATCH 512
#define NN    32
#define NVT   32
#define HS    501
#define VS    533
#define KP    512

typedef short bf16x8 __attribute__((ext_vector_type(8)));
typedef float f32x4  __attribute__((ext_vector_type(4)));

__device__ __forceinline__ unsigned short f2bf(float f) {
    unsigned int u = __float_as_uint(f);
    u += 0x7fffu + ((u >> 16) & 1u);
    return (unsigned short)(u >> 16);
}
__device__ __forceinline__ float bf2f(unsigned short s) {
    return __uint_as_float(((unsigned int)s) << 16);
}
__device__ __forceinline__ float sigmoidf_(float x) { return 1.0f / (1.0f + __expf(-x)); }
__device__ __forceinline__ float tanhf_(float x)    { return 1.0f - 2.0f / (1.0f + __expf(2.0f * x)); }

#define N_WHH  (3 * KP * KP)
#define N_WGM  (2 * KP * KP)
#define N_GI   (3 * NVT * KP)
#define N_IDW  (2 * NN * KP)
#define N_WRT  (KP * NN)
#define N_MSGB (BATCH * KP)
#define N_ADJC (BATCH * NN)
#define N_TOT  (N_WHH + N_WGM + N_GI + N_IDW + N_WRT + N_MSGB + N_ADJC)

__global__ void prep_kernel(const float* __restrict__ W_hh, const float* __restrict__ Wg,
                            const float* __restrict__ Wm, const float* __restrict__ W_ih,
                            const float* __restrict__ b_ih, const float* __restrict__ b_hh,
                            const float* __restrict__ bg, const float* __restrict__ W_reg,
                            const float* __restrict__ adj,
                            unsigned short* __restrict__ Whh_p, unsigned short* __restrict__ Wgm_p,
                            float* __restrict__ gi_tab, float* __restrict__ idw,
                            float* __restrict__ WregT, unsigned short* __restrict__ MsgB,
                            unsigned int* __restrict__ adjcG)
{
    for (int i = blockIdx.x * blockDim.x + threadIdx.x; i < N_TOT; i += gridDim.x * blockDim.x) {
        int j = i;
        if (j < N_WHH) {
            int g = j >> 18, rem = j & (KP * KP - 1);
            int h = rem >> 9, k = rem & (KP - 1);
            float val = 0.0f;
            if (h < HS) {
                if (k < HS)        val = W_hh[(size_t)(g * HS + h) * HS + k];
                else if (k == HS)  val = b_hh[g * HS + h];   // bias folded at k=501
            }
            Whh_p[j] = f2bf(val);
            continue;
        }
        j -= N_WHH;
        if (j < N_WGM) {
            int m = j >> 18, rem = j & (KP * KP - 1);
            int h = rem >> 9, k = rem & (KP - 1);
            const float* src = m ? Wm : Wg;
            Wgm_p[j] = (h < HS && k < HS) ? f2bf(src[(size_t)h * VS + k]) : (unsigned short)0;
            continue;
        }
        j -= N_WGM;
        if (j < N_GI) {
            int g = j >> 14, typ = (j >> 9) & 31, h = j & (KP - 1);
            gi_tab[j] = (h < HS) ? (W_ih[(size_t)(g * HS + h) * NVT + typ] + b_ih[g * HS + h]) : 0.0f;
            continue;
        }
        j -= N_GI;
        if (j < N_IDW) {
            int m = j >> 14, v = (j >> 9) & 31, h = j & (KP - 1);
            float val = 0.0f;
            if (h < HS)
                val = m ? Wm[(size_t)h * VS + HS + v]
                        : (Wg[(size_t)h * VS + HS + v] + bg[h]);
            idw[j] = val;
            continue;
        }
        j -= N_IDW;
        if (j < N_WRT) {
            int k = j >> 5, ii = j & 31;
            WregT[j] = (k < HS) ? W_reg[(size_t)ii * HS + k] : 0.0f;
            continue;
        }
        j -= N_WRT;
        if (j < N_MSGB) {
            int k = j & (KP - 1);
            MsgB[j] = (k == HS) ? (unsigned short)0x3F80 : (unsigned short)0;  // bias col = 1.0
            continue;
        }
        j -= N_MSGB;
        {
            int b = j >> 5, vp = j & 31;
            unsigned int bits = 0;
            #pragma unroll
            for (int u = 0; u < 32; u++)
                bits |= (adj[((size_t)b * NN + u) * NN + vp] != 0.0f ? 1u : 0u) << u;
            adjcG[j] = bits;
        }
    }
}

// slice barrier: 32 blocks (all on ONE XCD by construction). Relaxed device-scope
// atomics, no fences: __syncthreads drained stores to the shared XCD L2 already;
// consumers use volatile (sc0) loads that bypass L1.
__device__ __forceinline__ void sbar(unsigned int* cnt, unsigned int target) {
    __syncthreads();
    if (threadIdx.x == 0) {
        __hip_atomic_fetch_add(cnt, 1u, __ATOMIC_RELAXED, __HIP_MEMORY_SCOPE_AGENT);
        while (__hip_atomic_load(cnt, __ATOMIC_RELAXED, __HIP_MEMORY_SCOPE_AGENT) < target)
            __builtin_amdgcn_s_sleep(1);
    }
    __syncthreads();
}

// Persistent: 1024 blocks launched; 32 workers per XCD self-assigned.
// Worker (xcd, slot): batch-group = xcd (64 rows), h-block = slot (16 h-cols).
// Weights for its h-cols live in LDS for the whole run. Slice = one XCD ->
// all cross-block traffic stays in that XCD's L2.
__global__ __launch_bounds__(512, 1) void dvae_kernel(
    const unsigned short* __restrict__ Whh,   // [3*512][512] bf16 (k=501 = b_hh)
    const unsigned short* __restrict__ Wgm,   // [2*512][512] bf16
    const float* __restrict__ gi_tab,         // [3][32][512]
    const float* __restrict__ idw,            // [2][32][512]
    const int*   __restrict__ types,          // [512][32]
    const unsigned int* __restrict__ adjcG,   // [512][32] bitmask over u
    unsigned short* __restrict__ MsgB,        // [512][512] bf16 (+bias col 501)
    unsigned short* __restrict__ HvB,         // [512][512] bf16
    unsigned short* __restrict__ Ghist,       // [256 role][32 u][64 b][16 h] bf16
    float* __restrict__ HvF,                  // [512][512] f32 (final step)
    unsigned int* __restrict__ cb)            // [0..7] claim, [8..15] barrier
{
    __shared__ unsigned short WLDS[80 * 512];     // 80 KB swizzled weights
    __shared__ float          Cred[12 * 256];     // 12 KB K-split reduce
    __shared__ float          MsgF_L[64 * 16];    // 4 KB f32 Msg mirror (own patch)
    __shared__ unsigned short GvL[64 * 16];       // 2 KB G_v staging
    __shared__ unsigned int   adjcL[64 * 32];     // 8 KB
    __shared__ int            slotS;

    // ---- self-assignment: slice == XCD ----
    int xcd;
    asm volatile("s_getreg_b32 %0, hwreg(HW_REG_XCC_ID)" : "=s"(xcd));
    xcd &= 7;
    if (threadIdx.x == 0)
        slotS = (int)__hip_atomic_fetch_add(&cb[xcd], 1u, __ATOMIC_RELAXED,
                                            __HIP_MEMORY_SCOPE_AGENT);
    __syncthreads();
    const int slot = slotS;
    if (slot >= 32) return;                      // surplus block
    const int hblk = slot, bslc = xcd;
    unsigned int* cnt = cb + 8 + bslc;

    const int t    = threadIdx.x;
    const int lane = t & 63, w = t >> 6;          // 8 waves
    const int c16  = lane & 15, kg = lane >> 4;
    const int bt   = w & 3, kh = w >> 2;          // wave: batch-tile x K-half

    // ---- stage weights into LDS (row R in [0,80) = [Whh 48 | Wgm 32], swizzled)
    for (int i = 0; i < 10; i++) {
        const int seg = i * 512 + t;
        const int R = seg >> 6, k8 = (seg & 63) * 8;
        const unsigned short* src;
        if (R < 48) {
            const int g = R >> 4, r = R & 15;
            src = Whh + (((size_t)(g * 512 + hblk * 16 + r)) << 9) + k8;
        } else {
            const int m = (R - 48) >> 4, r = (R - 48) & 15;
            src = Wgm + (((size_t)(m * 512 + hblk * 16 + r)) << 9) + k8;
        }
        const bf16x8 val = *(const bf16x8*)src;
        const int didx = ((R << 10) + (k8 << 1)) ^ ((R & 7) << 4);   // byte, swizzled
        *(bf16x8*)&WLDS[didx >> 1] = val;
    }
    for (int i = t; i < 64 * 32; i += 512) adjcL[i] = adjcG[bslc * (64 * 32) + i];
    for (int i = t; i < 64 * 16; i += 512) MsgF_L[i] = 0.0f;
    __syncthreads();

    unsigned short* Gblk = Ghist + (size_t)(bslc * 32 + hblk) * (32 * 64 * 16);
    unsigned int ph = 0;

    for (int v = 0; v < NN; v++) {
        // ======== phase A: gh = Msg @ Whh^T (own 16 h-cols, 64 rows, split-K2) ========
        f32x4 a0 = {0.f,0.f,0.f,0.f}, a1 = a0, a2 = a0;
        {
            const volatile unsigned short* aptr =
                MsgB + (((size_t)(bslc * 64 + bt * 16 + c16)) << 9) + kh * 256 + kg * 8;
            const int wi0 = (((c16 << 10) + ((kh * 256 + kg * 8) << 1)) ^ ((c16 & 7) << 4)) >> 1;
            const int wi1 = wi0 + 8192, wi2 = wi0 + 16384;
            #pragma unroll
            for (int kk = 0; kk < 8; kk++) {
                const bf16x8 af = *(const volatile bf16x8*)(aptr + kk * 32);
                a0 = __builtin_amdgcn_mfma_f32_16x16x32_bf16(af, *(const bf16x8*)&WLDS[wi0 ^ (kk*32)], a0, 0, 0, 0);
                a1 = __builtin_amdgcn_mfma_f32_16x16x32_bf16(af, *(const bf16x8*)&WLDS[wi1 ^ (kk*32)], a1, 0, 0, 0);
                a2 = __builtin_amdgcn_mfma_f32_16x16x32_bf16(af, *(const bf16x8*)&WLDS[wi2 ^ (kk*32)], a2, 0, 0, 0);
            }
        }
        if (kh == 1) {
            #pragma unroll
            for (int j = 0; j < 4; j++) {
                const int pi = (kg * 4 + j) * 16 + c16;
                Cred[(bt * 3 + 0) * 256 + pi] = a0[j];
                Cred[(bt * 3 + 1) * 256 + pi] = a1[j];
                Cred[(bt * 3 + 2) * 256 + pi] = a2[j];
            }
        }
        __syncthreads();
        if (kh == 0) {
            const int h = hblk * 16 + c16;
            const bool ok = (h < HS);
            #pragma unroll
            for (int j = 0; j < 4; j++) {
                const int pi = (kg * 4 + j) * 16 + c16;
                const float s0 = a0[j] + Cred[(bt * 3 + 0) * 256 + pi];
                const float s1 = a1[j] + Cred[(bt * 3 + 1) * 256 + pi];
                const float s2 = a2[j] + Cred[(bt * 3 + 2) * 256 + pi];
                const int bl = bt * 16 + kg * 4 + j;
                const int bg_ = bslc * 64 + bl;
                float hv = 0.0f;
                if (ok) {
                    const int typ = types[bg_ * 32 + v];
                    const float gr = gi_tab[(0 * 32 + typ) * 512 + h];
                    const float gz = gi_tab[(1 * 32 + typ) * 512 + h];
                    const float gn = gi_tab[(2 * 32 + typ) * 512 + h];
                    const float hmsg = MsgF_L[bl * 16 + c16];
                    const float r = sigmoidf_(gr + s0);
                    const float z = sigmoidf_(gz + s1);
                    const float n = tanhf_(gn + r * s2);
                    hv = (1.0f - z) * n + z * hmsg;
                }
                HvB[((size_t)bg_ << 9) + h] = f2bf(hv);
                if (v == NN - 1) HvF[((size_t)bg_ << 9) + h] = hv;
            }
        }
        if (v == NN - 1) break;
        sbar(cnt, 32u * (++ph));

        // ======== phase B: z = Hv @ {Wg,Wm}^T ========
        f32x4 b0 = {0.f,0.f,0.f,0.f}, b1 = b0;
        {
            const volatile unsigned short* aptr =
                HvB + (((size_t)(bslc * 64 + bt * 16 + c16)) << 9) + kh * 256 + kg * 8;
            const int wi0 = ((((48 + c16) << 10) + ((kh * 256 + kg * 8) << 1)) ^ ((c16 & 7) << 4)) >> 1;
            const int wi1 = wi0 + 8192;
            #pragma unroll
            for (int kk = 0; kk < 8; kk++) {
                const bf16x8 af = *(const volatile bf16x8*)(aptr + kk * 32);
                b0 = __builtin_amdgcn_mfma_f32_16x16x32_bf16(af, *(const bf16x8*)&WLDS[wi0 ^ (kk*32)], b0, 0, 0, 0);
                b1 = __builtin_amdgcn_mfma_f32_16x16x32_bf16(af, *(const bf16x8*)&WLDS[wi1 ^ (kk*32)], b1, 0, 0, 0);
            }
        }
        if (kh == 1) {
            #pragma unroll
            for (int j = 0; j < 4; j++) {
                const int pi = (kg * 4 + j) * 16 + c16;
                Cred[(bt * 2 + 0) * 256 + pi] = b0[j];
                Cred[(bt * 2 + 1) * 256 + pi] = b1[j];
            }
        }
        __syncthreads();
        if (kh == 0) {
            const int h = hblk * 16 + c16;
            const bool ok = (h < HS);
            #pragma unroll
            for (int j = 0; j < 4; j++) {
                const int pi = (kg * 4 + j) * 16 + c16;
                const float s0 = b0[j] + Cred[(bt * 2 + 0) * 256 + pi];
                const float s1 = b1[j] + Cred[(bt * 2 + 1) * 256 + pi];
                const int bl = bt * 16 + kg * 4 + j;
                float gq = 0.0f;
                if (ok) {
                    const float zg = s0 + idw[(0 * 32 + v) * 512 + h];
                    const float zm = s1 + idw[(1 * 32 + v) * 512 + h];
                    gq = sigmoidf_(zg) * zm;
                }
                GvL[bl * 16 + c16] = f2bf(gq);
            }
        }
        __syncthreads();
        // ---- gather: persist G_v (block-private), assemble Msg_{v+1} own patch
        if (t < 128) {
            const int bl = t >> 1, h8 = (t & 1) * 8;
            const bf16x8 g = *(const bf16x8*)&GvL[bl * 16 + h8];
            *(bf16x8*)&Gblk[((size_t)v * 64 + bl) * 16 + h8] = g;

            float msg[8] = {0.f,0.f,0.f,0.f,0.f,0.f,0.f,0.f};
            unsigned int mask = adjcL[bl * 32 + (v + 1)] & ((2u << v) - 1u);   // u <= v
            if ((mask >> v) & 1u) {
                #pragma unroll
                for (int x = 0; x < 8; x++) msg[x] += bf2f((unsigned short)g[x]);
                mask &= ~(1u << v);
            }
            while (mask) {
                const int u = __builtin_ctz(mask); mask &= mask - 1u;
                const bf16x8 a = *(const bf16x8*)&Gblk[((size_t)u * 64 + bl) * 16 + h8];
                #pragma unroll
                for (int x = 0; x < 8; x++) msg[x] += bf2f((unsigned short)a[x]);
            }
            const int hb_ = hblk * 16 + h8;
            if (hb_ <= HS && HS < hb_ + 8) msg[HS - hb_] = 1.0f;   // bias col k=501
            bf16x8 mb;
            #pragma unroll
            for (int x = 0; x < 8; x++) mb[x] = (short)f2bf(msg[x]);
            *(bf16x8*)&MsgB[(((size_t)(bslc * 64 + bl)) << 9) + hb_] = mb;
            #pragma unroll
            for (int x = 0; x < 8; x++) MsgF_L[bl * 16 + h8 + x] = msg[x];
        }
        sbar(cnt, 32u * (++ph));
    }
}

// mu = Hv31 @ W_reg^T + b_reg
__global__ __launch_bounds__(256) void final_kernel(
    const float* __restrict__ HvF,       // [512][512]
    const float* __restrict__ WregT,     // [512][32]
    const float* __restrict__ b_reg,     // [32]
    float* __restrict__ out)             // [512][32]
{
    const int t = blockIdx.x * 256 + threadIdx.x;
    const int b = t >> 5, i = t & 31;
    float s = b_reg[i];
    const float* hp = HvF + ((size_t)b << 9);
    #pragma unroll 4
    for (int k = 0; k < KP; k++) s += hp[k] * WregT[k * 32 + i];
    out[b * 32 + i] = s;
}

extern "C" void kernel_launch(void* const* d_in, const int* in_sizes, int n_in,
                              void* d_out, int out_size, void* d_ws, size_t ws_size,
                              hipStream_t stream) {
    const int*   node_types = (const int*)  d_in[0];
    const float* adj        = (const float*)d_in[1];
    const float* Wg         = (const float*)d_in[2];
    const float* bg         = (const float*)d_in[3];
    const float* Wm         = (const float*)d_in[4];
    const float* W_ih       = (const float*)d_in[5];
    const float* b_ih       = (const float*)d_in[6];
    const float* W_hh       = (const float*)d_in[7];
    const float* b_hh       = (const float*)d_in[8];
    const float* W_reg      = (const float*)d_in[9];
    const float* b_reg      = (const float*)d_in[10];
    float* out = (float*)d_out;

    char* p = (char*)d_ws;
    unsigned short* Whh_p = (unsigned short*)p; p += (size_t)N_WHH * 2;
    unsigned short* Wgm_p = (unsigned short*)p; p += (size_t)N_WGM * 2;
    float* gi_tab = (float*)p; p += (size_t)N_GI * 4;
    float* idw    = (float*)p; p += (size_t)N_IDW * 4;
    float* WregT  = (float*)p; p += (size_t)N_WRT * 4;
    float* HvF    = (float*)p; p += (size_t)BATCH * KP * 4;
    unsigned short* MsgB = (unsigned short*)p; p += (size_t)N_MSGB * 2;
    unsigned short* HvB  = (unsigned short*)p; p += (size_t)BATCH * KP * 2;
    unsigned int* adjcG  = (unsigned int*)p;  p += (size_t)N_ADJC * 4;
    unsigned int* cb     = (unsigned int*)p;  p += 16 * 4;
    unsigned short* Ghist = (unsigned short*)p; p += (size_t)256 * 32 * 64 * 16 * 2;

    hipMemsetAsync(cb, 0, 16 * 4, stream);
    prep_kernel<<<1024, 256, 0, stream>>>(W_hh, Wg, Wm, W_ih, b_ih, b_hh, bg, W_reg, adj,
                                          Whh_p, Wgm_p, gi_tab, idw, WregT, MsgB, adjcG);
    dvae_kernel<<<1024, 512, 0, stream>>>(Whh_p, Wgm_p, gi_tab, idw, node_types, adjcG,
                                          MsgB, HvB, Ghist, HvF, cb);
    final_kernel<<<(BATCH * NN) / 256, 256, 0, stream>>>(HvF, WregT, b_reg, out);
}

// Round 13
// 396.586 us; speedup vs baseline: 6.7152x; 1.1277x over previous
//
#include <hip/hip_runtime.h>

#define BATCH 512
#define NN    32
#define NVT   32
#define HS    501
#define VS    533
#define KP    512

typedef short bf16x8 __attribute__((ext_vector_type(8)));
typedef float f32x4  __attribute__((ext_vector_type(4)));

__device__ __forceinline__ unsigned short f2bf(float f) {
    unsigned int u = __float_as_uint(f);
    u += 0x7fffu + ((u >> 16) & 1u);
    return (unsigned short)(u >> 16);
}
__device__ __forceinline__ float bf2f(unsigned short s) {
    return __uint_as_float(((unsigned int)s) << 16);
}
__device__ __forceinline__ float sigmoidf_(float x) { return 1.0f / (1.0f + __expf(-x)); }
__device__ __forceinline__ float tanhf_(float x)    { return 1.0f - 2.0f / (1.0f + __expf(2.0f * x)); }

#define N_WHH  (3 * KP * KP)
#define N_WGM  (2 * KP * KP)
#define N_GI   (3 * NVT * KP)
#define N_IDW  (2 * NN * KP)
#define N_WRT  (KP * NN)
#define N_MSGB (BATCH * KP)
#define N_ADJC (BATCH * NN)
#define N_TOT  (N_WHH + N_WGM + N_GI + N_IDW + N_WRT + N_MSGB + N_ADJC)

// cb layout (u32): [0..7] claim counters; [16 .. 16+8*512) arrival flags
// (per XCD: 32 slots x 16-u32 stride = 64B/slot); [16+4096 .. +8*16) release words.
#define CB_WORDS (16 + 8 * 512 + 8 * 16)

__global__ void prep_kernel(const float* __restrict__ W_hh, const float* __restrict__ Wg,
                            const float* __restrict__ Wm, const float* __restrict__ W_ih,
                            const float* __restrict__ b_ih, const float* __restrict__ b_hh,
                            const float* __restrict__ bg, const float* __restrict__ W_reg,
                            const float* __restrict__ adj,
                            unsigned short* __restrict__ Whh_p, unsigned short* __restrict__ Wgm_p,
                            float* __restrict__ gi_tab, float* __restrict__ idw,
                            float* __restrict__ WregT, unsigned short* __restrict__ MsgB,
                            unsigned int* __restrict__ adjcG)
{
    for (int i = blockIdx.x * blockDim.x + threadIdx.x; i < N_TOT; i += gridDim.x * blockDim.x) {
        int j = i;
        if (j < N_WHH) {
            int g = j >> 18, rem = j & (KP * KP - 1);
            int h = rem >> 9, k = rem & (KP - 1);
            float val = 0.0f;
            if (h < HS) {
                if (k < HS)        val = W_hh[(size_t)(g * HS + h) * HS + k];
                else if (k == HS)  val = b_hh[g * HS + h];   // bias folded at k=501
            }
            Whh_p[j] = f2bf(val);
            continue;
        }
        j -= N_WHH;
        if (j < N_WGM) {
            int m = j >> 18, rem = j & (KP * KP - 1);
            int h = rem >> 9, k = rem & (KP - 1);
            const float* src = m ? Wm : Wg;
            Wgm_p[j] = (h < HS && k < HS) ? f2bf(src[(size_t)h * VS + k]) : (unsigned short)0;
            continue;
        }
        j -= N_WGM;
        if (j < N_GI) {
            int g = j >> 14, typ = (j >> 9) & 31, h = j & (KP - 1);
            gi_tab[j] = (h < HS) ? (W_ih[(size_t)(g * HS + h) * NVT + typ] + b_ih[g * HS + h]) : 0.0f;
            continue;
        }
        j -= N_GI;
        if (j < N_IDW) {
            int m = j >> 14, v = (j >> 9) & 31, h = j & (KP - 1);
            float val = 0.0f;
            if (h < HS)
                val = m ? Wm[(size_t)h * VS + HS + v]
                        : (Wg[(size_t)h * VS + HS + v] + bg[h]);
            idw[j] = val;
            continue;
        }
        j -= N_IDW;
        if (j < N_WRT) {
            int k = j >> 5, ii = j & 31;
            WregT[j] = (k < HS) ? W_reg[(size_t)ii * HS + k] : 0.0f;
            continue;
        }
        j -= N_WRT;
        if (j < N_MSGB) {
            int k = j & (KP - 1);
            MsgB[j] = (k == HS) ? (unsigned short)0x3F80 : (unsigned short)0;  // bias col = 1.0
            continue;
        }
        j -= N_MSGB;
        {
            int b = j >> 5, vp = j & 31;
            unsigned int bits = 0;
            #pragma unroll
            for (int u = 0; u < 32; u++)
                bits |= (adj[((size_t)b * NN + u) * NN + vp] != 0.0f ? 1u : 0u) << u;
            adjcG[j] = bits;
        }
    }
}

// Contention-free slice barrier (32 blocks, one XCD). Arrival: plain relaxed store
// to own 64B slot. Master (slot 0): wave-parallel poll of all 32 flags. Release:
// single word others poll read-only. Data visibility: __syncthreads drains vmcnt
// (stores in L2) before arrival store; consumers use volatile/sc0 loads.
__device__ __forceinline__ void sbar(unsigned int* flags, unsigned int* rel,
                                     int slot, unsigned int ph) {
    __syncthreads();
    const int t = threadIdx.x;
    if (t < 64) {
        if (t == 0)
            __hip_atomic_store(&flags[slot * 16], ph, __ATOMIC_RELAXED,
                               __HIP_MEMORY_SCOPE_AGENT);
        if (slot == 0) {
            unsigned long long notready;
            do {
                const unsigned int fv = (t < 32)
                    ? __hip_atomic_load(&flags[t * 16], __ATOMIC_RELAXED,
                                        __HIP_MEMORY_SCOPE_AGENT)
                    : ph;
                notready = __ballot(fv < ph);
                if (notready) __builtin_amdgcn_s_sleep(2);
            } while (notready);
            if (t == 0)
                __hip_atomic_store(rel, ph, __ATOMIC_RELAXED, __HIP_MEMORY_SCOPE_AGENT);
        } else if (t == 0) {
            while (__hip_atomic_load(rel, __ATOMIC_RELAXED, __HIP_MEMORY_SCOPE_AGENT) < ph)
                __builtin_amdgcn_s_sleep(2);
        }
    }
    __syncthreads();
}

// Persistent: 1024 blocks launched; 32 workers per XCD self-assigned.
// Worker (xcd, slot): batch-group = xcd (64 rows), h-block = slot (16 h-cols).
// Weights live in LDS for the whole run; cross-block traffic stays in-XCD L2.
__global__ __launch_bounds__(512, 1) void dvae_kernel(
    const unsigned short* __restrict__ Whh,   // [3*512][512] bf16 (k=501 = b_hh)
    const unsigned short* __restrict__ Wgm,   // [2*512][512] bf16
    const float* __restrict__ gi_tab,         // [3][32][512]
    const float* __restrict__ idw,            // [2][32][512]
    const int*   __restrict__ types,          // [512][32]
    const unsigned int* __restrict__ adjcG,   // [512][32] bitmask over u
    unsigned short* __restrict__ MsgB,        // [512][512] bf16 (+bias col 501)
    unsigned short* __restrict__ HvB,         // [512][512] bf16
    unsigned short* __restrict__ Ghist,       // [256 role][32 u][64 b][16 h] bf16
    float* __restrict__ HvF,                  // [512][512] f32 (final step)
    unsigned int* __restrict__ cb)            // claim + flags + release
{
    __shared__ unsigned short WLDS[80 * 512];     // 80 KB swizzled weights
    __shared__ float          Cred[12 * 256];     // 12 KB K-split reduce
    __shared__ float          MsgF_L[64 * 16];    // 4 KB f32 Msg mirror (own patch)
    __shared__ unsigned short GvL[64 * 16];       // 2 KB G_v staging
    __shared__ unsigned int   adjcL[64 * 32];     // 8 KB
    __shared__ int            slotS;

    // ---- self-assignment: slice == XCD ----
    int xcd;
    asm volatile("s_getreg_b32 %0, hwreg(HW_REG_XCC_ID)" : "=s"(xcd));
    xcd &= 7;
    if (threadIdx.x == 0)
        slotS = (int)__hip_atomic_fetch_add(&cb[xcd], 1u, __ATOMIC_RELAXED,
                                            __HIP_MEMORY_SCOPE_AGENT);
    __syncthreads();
    const int slot = slotS;
    if (slot >= 32) return;                      // surplus block
    const int hblk = slot, bslc = xcd;
    unsigned int* flags = cb + 16 + (bslc << 9);
    unsigned int* rel   = cb + 16 + 4096 + (bslc << 4);

    const int t    = threadIdx.x;
    const int lane = t & 63, w = t >> 6;          // 8 waves
    const int c16  = lane & 15, kg = lane >> 4;
    const int bt   = w & 3, kh = w >> 2;          // wave: batch-tile x K-half

    // ---- stage weights into LDS (row R in [0,80) = [Whh 48 | Wgm 32], swizzled)
    for (int i = 0; i < 10; i++) {
        const int seg = i * 512 + t;
        const int R = seg >> 6, k8 = (seg & 63) * 8;
        const unsigned short* src;
        if (R < 48) {
            const int g = R >> 4, r = R & 15;
            src = Whh + (((size_t)(g * 512 + hblk * 16 + r)) << 9) + k8;
        } else {
            const int m = (R - 48) >> 4, r = (R - 48) & 15;
            src = Wgm + (((size_t)(m * 512 + hblk * 16 + r)) << 9) + k8;
        }
        const bf16x8 val = *(const bf16x8*)src;
        const int didx = ((R << 10) + (k8 << 1)) ^ ((R & 7) << 4);   // byte, swizzled
        *(bf16x8*)&WLDS[didx >> 1] = val;
    }
    for (int i = t; i < 64 * 32; i += 512) adjcL[i] = adjcG[bslc * (64 * 32) + i];
    for (int i = t; i < 64 * 16; i += 512) MsgF_L[i] = 0.0f;
    __syncthreads();

    unsigned short* Gblk = Ghist + (size_t)(bslc * 32 + hblk) * (32 * 64 * 16);
    unsigned int ph = 0;

    for (int v = 0; v < NN; v++) {
        // ======== phase A: gh = Msg @ Whh^T (own 16 h-cols, 64 rows, split-K2) ========
        f32x4 a0 = {0.f,0.f,0.f,0.f}, a1 = a0, a2 = a0;
        {
            const volatile unsigned short* aptr =
                MsgB + (((size_t)(bslc * 64 + bt * 16 + c16)) << 9) + kh * 256 + kg * 8;
            const int wi0 = (((c16 << 10) + ((kh * 256 + kg * 8) << 1)) ^ ((c16 & 7) << 4)) >> 1;
            const int wi1 = wi0 + 8192, wi2 = wi0 + 16384;
            #pragma unroll
            for (int kk = 0; kk < 8; kk++) {
                const bf16x8 af = *(const volatile bf16x8*)(aptr + kk * 32);
                a0 = __builtin_amdgcn_mfma_f32_16x16x32_bf16(af, *(const bf16x8*)&WLDS[wi0 ^ (kk*32)], a0, 0, 0, 0);
                a1 = __builtin_amdgcn_mfma_f32_16x16x32_bf16(af, *(const bf16x8*)&WLDS[wi1 ^ (kk*32)], a1, 0, 0, 0);
                a2 = __builtin_amdgcn_mfma_f32_16x16x32_bf16(af, *(const bf16x8*)&WLDS[wi2 ^ (kk*32)], a2, 0, 0, 0);
            }
        }
        if (kh == 1) {
            #pragma unroll
            for (int j = 0; j < 4; j++) {
                const int pi = (kg * 4 + j) * 16 + c16;
                Cred[(bt * 3 + 0) * 256 + pi] = a0[j];
                Cred[(bt * 3 + 1) * 256 + pi] = a1[j];
                Cred[(bt * 3 + 2) * 256 + pi] = a2[j];
            }
        }
        __syncthreads();
        if (kh == 0) {
            const int h = hblk * 16 + c16;
            const bool ok = (h < HS);
            #pragma unroll
            for (int j = 0; j < 4; j++) {
                const int pi = (kg * 4 + j) * 16 + c16;
                const float s0 = a0[j] + Cred[(bt * 3 + 0) * 256 + pi];
                const float s1 = a1[j] + Cred[(bt * 3 + 1) * 256 + pi];
                const float s2 = a2[j] + Cred[(bt * 3 + 2) * 256 + pi];
                const int bl = bt * 16 + kg * 4 + j;
                const int bg_ = bslc * 64 + bl;
                float hv = 0.0f;
                if (ok) {
                    const int typ = types[bg_ * 32 + v];
                    const float gr = gi_tab[(0 * 32 + typ) * 512 + h];
                    const float gz = gi_tab[(1 * 32 + typ) * 512 + h];
                    const float gn = gi_tab[(2 * 32 + typ) * 512 + h];
                    const float hmsg = MsgF_L[bl * 16 + c16];
                    const float r = sigmoidf_(gr + s0);
                    const float z = sigmoidf_(gz + s1);
                    const float n = tanhf_(gn + r * s2);
                    hv = (1.0f - z) * n + z * hmsg;
                }
                HvB[((size_t)bg_ << 9) + h] = f2bf(hv);
                if (v == NN - 1) HvF[((size_t)bg_ << 9) + h] = hv;
            }
        }
        if (v == NN - 1) break;
        sbar(flags, rel, hblk, ++ph);

        // ======== phase B: z = Hv @ {Wg,Wm}^T ========
        f32x4 b0 = {0.f,0.f,0.f,0.f}, b1 = b0;
        {
            const volatile unsigned short* aptr =
                HvB + (((size_t)(bslc * 64 + bt * 16 + c16)) << 9) + kh * 256 + kg * 8;
            const int wi0 = ((((48 + c16) << 10) + ((kh * 256 + kg * 8) << 1)) ^ ((c16 & 7) << 4)) >> 1;
            const int wi1 = wi0 + 8192;
            #pragma unroll
            for (int kk = 0; kk < 8; kk++) {
                const bf16x8 af = *(const volatile bf16x8*)(aptr + kk * 32);
                b0 = __builtin_amdgcn_mfma_f32_16x16x32_bf16(af, *(const bf16x8*)&WLDS[wi0 ^ (kk*32)], b0, 0, 0, 0);
                b1 = __builtin_amdgcn_mfma_f32_16x16x32_bf16(af, *(const bf16x8*)&WLDS[wi1 ^ (kk*32)], b1, 0, 0, 0);
            }
        }
        if (kh == 1) {
            #pragma unroll
            for (int j = 0; j < 4; j++) {
                const int pi = (kg * 4 + j) * 16 + c16;
                Cred[(bt * 2 + 0) * 256 + pi] = b0[j];
                Cred[(bt * 2 + 1) * 256 + pi] = b1[j];
            }
        }
        __syncthreads();
        if (kh == 0) {
            const int h = hblk * 16 + c16;
            const bool ok = (h < HS);
            #pragma unroll
            for (int j = 0; j < 4; j++) {
                const int pi = (kg * 4 + j) * 16 + c16;
                const float s0 = b0[j] + Cred[(bt * 2 + 0) * 256 + pi];
                const float s1 = b1[j] + Cred[(bt * 2 + 1) * 256 + pi];
                const int bl = bt * 16 + kg * 4 + j;
                float gq = 0.0f;
                if (ok) {
                    const float zg = s0 + idw[(0 * 32 + v) * 512 + h];
                    const float zm = s1 + idw[(1 * 32 + v) * 512 + h];
                    gq = sigmoidf_(zg) * zm;
                }
                GvL[bl * 16 + c16] = f2bf(gq);
            }
        }
        __syncthreads();
        // ---- gather: persist G_v (block-private), assemble Msg_{v+1} own patch
        if (t < 128) {
            const int bl = t >> 1, h8 = (t & 1) * 8;
            const bf16x8 g = *(const bf16x8*)&GvL[bl * 16 + h8];
            *(bf16x8*)&Gblk[((size_t)v * 64 + bl) * 16 + h8] = g;

            float msg[8] = {0.f,0.f,0.f,0.f,0.f,0.f,0.f,0.f};
            unsigned int mask = adjcL[bl * 32 + (v + 1)] & ((2u << v) - 1u);   // u <= v
            if ((mask >> v) & 1u) {
                #pragma unroll
                for (int x = 0; x < 8; x++) msg[x] += bf2f((unsigned short)g[x]);
                mask &= ~(1u << v);
            }
            while (mask) {
                const int u = __builtin_ctz(mask); mask &= mask - 1u;
                const bf16x8 a = *(const bf16x8*)&Gblk[((size_t)u * 64 + bl) * 16 + h8];
                #pragma unroll
                for (int x = 0; x < 8; x++) msg[x] += bf2f((unsigned short)a[x]);
            }
            const int hb_ = hblk * 16 + h8;
            if (hb_ <= HS && HS < hb_ + 8) msg[HS - hb_] = 1.0f;   // bias col k=501
            bf16x8 mb;
            #pragma unroll
            for (int x = 0; x < 8; x++) mb[x] = (short)f2bf(msg[x]);
            *(bf16x8*)&MsgB[(((size_t)(bslc * 64 + bl)) << 9) + hb_] = mb;
            #pragma unroll
            for (int x = 0; x < 8; x++) MsgF_L[bl * 16 + h8 + x] = msg[x];
        }
        sbar(flags, rel, hblk, ++ph);
    }
}

// mu = Hv31 @ W_reg^T + b_reg
__global__ __launch_bounds__(256) void final_kernel(
    const float* __restrict__ HvF,       // [512][512]
    const float* __restrict__ WregT,     // [512][32]
    const float* __restrict__ b_reg,     // [32]
    float* __restrict__ out)             // [512][32]
{
    const int t = blockIdx.x * 256 + threadIdx.x;
    const int b = t >> 5, i = t & 31;
    float s = b_reg[i];
    const float* hp = HvF + ((size_t)b << 9);
    #pragma unroll 4
    for (int k = 0; k < KP; k++) s += hp[k] * WregT[k * 32 + i];
    out[b * 32 + i] = s;
}

extern "C" void kernel_launch(void* const* d_in, const int* in_sizes, int n_in,
                              void* d_out, int out_size, void* d_ws, size_t ws_size,
                              hipStream_t stream) {
    const int*   node_types = (const int*)  d_in[0];
    const float* adj        = (const float*)d_in[1];
    const float* Wg         = (const float*)d_in[2];
    const float* bg         = (const float*)d_in[3];
    const float* Wm         = (const float*)d_in[4];
    const float* W_ih       = (const float*)d_in[5];
    const float* b_ih       = (const float*)d_in[6];
    const float* W_hh       = (const float*)d_in[7];
    const float* b_hh       = (const float*)d_in[8];
    const float* W_reg      = (const float*)d_in[9];
    const float* b_reg      = (const float*)d_in[10];
    float* out = (float*)d_out;

    char* p = (char*)d_ws;
    unsigned short* Whh_p = (unsigned short*)p; p += (size_t)N_WHH * 2;
    unsigned short* Wgm_p = (unsigned short*)p; p += (size_t)N_WGM * 2;
    float* gi_tab = (float*)p; p += (size_t)N_GI * 4;
    float* idw    = (float*)p; p += (size_t)N_IDW * 4;
    float* WregT  = (float*)p; p += (size_t)N_WRT * 4;
    float* HvF    = (float*)p; p += (size_t)BATCH * KP * 4;
    unsigned short* MsgB = (unsigned short*)p; p += (size_t)N_MSGB * 2;
    unsigned short* HvB  = (unsigned short*)p; p += (size_t)BATCH * KP * 2;
    unsigned int* adjcG  = (unsigned int*)p;  p += (size_t)N_ADJC * 4;
    unsigned int* cb     = (unsigned int*)p;  p += (size_t)CB_WORDS * 4;
    unsigned short* Ghist = (unsigned short*)p; p += (size_t)256 * 32 * 64 * 16 * 2;

    hipMemsetAsync(cb, 0, CB_WORDS * 4, stream);
    prep_kernel<<<1024, 256, 0, stream>>>(W_hh, Wg, Wm, W_ih, b_ih, b_hh, bg, W_reg, adj,
                                          Whh_p, Wgm_p, gi_tab, idw, WregT, MsgB, adjcG);
    dvae_kernel<<<1024, 512, 0, stream>>>(Whh_p, Wgm_p, gi_tab, idw, node_types, adjcG,
                                          MsgB, HvB, Ghist, HvF, cb);
    final_kernel<<<(BATCH * NN) / 256, 256, 0, stream>>>(HvF, WregT, b_reg, out);
}